// Round 2
// baseline (77.456 us; speedup 1.0000x reference)
//
#include <hip/hip_runtime.h>

// STFT_7653631721942: STFT -> mag/phase recombine -> ISTFT with pinv basis +
// window-sum normalization. Mathematically this pipeline is the IDENTITY on
// the output window:
//   - recomb == ft  (mag*cos(atan2(i,r)) = r, mag*sin = i)
//   - pinv(F)F = I (F full column rank) => contrib[t,k] = w^2[k]*frame[k]/scale
//   - overlap-add / wss * scale => inv[p] = xpad[p] wherever wss[p] > tiny
//   - the output slice p in [512, 524800) lies entirely in the un-padded
//     region with wss >= 0.25, so output == input exactly.
// Hence: vectorized d2d copy, 8x524288 f32 = 16 MiB each way.
//
// R2: same plan as R1 (4 independent float4/thread + non-temporal), but with
// a clang-native ext_vector_type(4) float — __builtin_nontemporal_load/store
// rejects HIP_vector_type<float,4> (struct), accepts native vectors.

constexpr int BLOCK = 256;
constexpr int VPT = 4;  // 16B vectors per thread

typedef float f32x4 __attribute__((ext_vector_type(4)));

__global__ __launch_bounds__(BLOCK) void stft_identity_copy(
    const f32x4* __restrict__ in, f32x4* __restrict__ out, int n4) {
    int t = blockIdx.x * BLOCK + threadIdx.x;
    int T = gridDim.x * BLOCK;
    // 4 independent, individually-coalesced streams: i, i+T, i+2T, i+3T.
    #pragma unroll
    for (int j = 0; j < VPT; ++j) {
        int i = t + j * T;
        if (i < n4) {
            f32x4 v = __builtin_nontemporal_load(&in[i]);
            __builtin_nontemporal_store(v, &out[i]);
        }
    }
}

__global__ __launch_bounds__(BLOCK) void stft_identity_copy_tail(
    const float* __restrict__ in, float* __restrict__ out, int start, int n) {
    int i = start + blockIdx.x * BLOCK + threadIdx.x;
    if (i < n) out[i] = in[i];
}

extern "C" void kernel_launch(void* const* d_in, const int* in_sizes, int n_in,
                              void* d_out, int out_size, void* d_ws, size_t ws_size,
                              hipStream_t stream) {
    const float* in = (const float*)d_in[0];   // input_data, 8 x 524288 f32
    float* out = (float*)d_out;                // 8 x 1 x 524288 f32

    int n = out_size;          // 4194304 floats
    int n4 = n >> 2;           // 1048576 16B vectors

    int grid = (n4 + BLOCK * VPT - 1) / (BLOCK * VPT);   // 1024 blocks
    stft_identity_copy<<<grid, BLOCK, 0, stream>>>(
        (const f32x4*)in, (f32x4*)out, n4);

    int tail_start = n4 << 2;
    int tail = n - tail_start;  // 0 for this problem, kept for safety
    if (tail > 0) {
        int tgrid = (tail + BLOCK - 1) / BLOCK;
        stft_identity_copy_tail<<<tgrid, BLOCK, 0, stream>>>(in, out, tail_start, n);
    }
}

// Round 3
// 73.830 us; speedup vs baseline: 1.0491x; 1.0491x over previous
//
#include <hip/hip_runtime.h>

// STFT_7653631721942: STFT -> mag/phase recombine -> ISTFT with pinv basis +
// window-sum normalization. Mathematically this pipeline is the IDENTITY on
// the output window:
//   - recomb == ft  (mag*cos(atan2(i,r)) = r, mag*sin = i)
//   - pinv(F)F = I (F full column rank) => contrib[t,k] = w^2[k]*frame[k]/scale
//   - overlap-add / wss * scale => inv[p] = xpad[p] wherever wss[p] > tiny
//   - the output slice p in [512, 524800) lies entirely in the un-padded
//     region with wss >= 0.25, so output == input exactly.
// Hence: vectorized d2d copy, 8x524288 f32 = 16 MiB each way.
//
// R3: REVERT to the R0 configuration (best measured: 73.7 us).
// R2's MLP + non-temporal experiment measured 77.5 us (worse/noise):
// the timed region is dominated by a fixed harness poison fill
// (256 MiB @ ~43 us, 78% HBM peak) + restore dispatches; the copy itself
// (~33.5 MB total traffic, ~6 us ideal) is a minor term and the simple
// 1-float4/thread form is as fast as any variant tried.

__global__ __launch_bounds__(256) void stft_identity_copy(
    const float4* __restrict__ in, float4* __restrict__ out, int n4) {
    int i = blockIdx.x * blockDim.x + threadIdx.x;
    if (i < n4) out[i] = in[i];
}

__global__ __launch_bounds__(256) void stft_identity_copy_tail(
    const float* __restrict__ in, float* __restrict__ out, int start, int n) {
    int i = start + blockIdx.x * blockDim.x + threadIdx.x;
    if (i < n) out[i] = in[i];
}

extern "C" void kernel_launch(void* const* d_in, const int* in_sizes, int n_in,
                              void* d_out, int out_size, void* d_ws, size_t ws_size,
                              hipStream_t stream) {
    const float* in = (const float*)d_in[0];   // input_data, 8 x 524288 f32
    float* out = (float*)d_out;                // 8 x 1 x 524288 f32

    int n = out_size;          // 4194304
    int n4 = n >> 2;           // 1048576 float4s (n is divisible by 4)

    const int block = 256;
    int grid = (n4 + block - 1) / block;
    stft_identity_copy<<<grid, block, 0, stream>>>(
        (const float4*)in, (float4*)out, n4);

    int tail_start = n4 << 2;
    int tail = n - tail_start;  // 0 for this problem, kept for safety
    if (tail > 0) {
        stft_identity_copy_tail<<<1, block, 0, stream>>>(in, out, tail_start, n);
    }
}